// Round 1
// baseline (18.070 us; speedup 1.0000x reference)
//
#include <hip/hip_runtime.h>
#include <hip/hip_bf16.h>

// Embedding gather with OOV handling.
// out[r][d] = (idx[r] >= VOCAB) ? oov[d] : emb[idx[r]][d]
// D = 200 floats = 50 float4 per row; rows are 800B => 16B aligned.
// One float4 per thread, coalesced output writes.

__global__ void embed_gather_kernel(const int* __restrict__ indices,
                                    const float4* __restrict__ emb,
                                    const float4* __restrict__ oov,
                                    float4* __restrict__ out,
                                    int n_vec,      // total float4 elements in output
                                    int vocab) {
    int i = blockIdx.x * blockDim.x + threadIdx.x;
    if (i >= n_vec) return;
    // 50 float4 per row (D=200)
    int row = i / 50;
    int v   = i - row * 50;
    int idx = indices[row];
    const float4* src = (idx >= vocab) ? (oov + v) : (emb + (long long)idx * 50 + v);
    out[i] = *src;
}

extern "C" void kernel_launch(void* const* d_in, const int* in_sizes, int n_in,
                              void* d_out, int out_size, void* d_ws, size_t ws_size,
                              hipStream_t stream) {
    const int*   indices = (const int*)d_in[0];
    const float* emb     = (const float*)d_in[1];
    const float* oov     = (const float*)d_in[2];
    float*       out     = (float*)d_out;

    const int D      = in_sizes[2];            // 200
    const int vocab  = in_sizes[1] / D;        // 100000
    const int n_vec  = out_size / 4;           // out_size = n_rows * 200, /4 for float4

    const int block = 256;
    const int grid  = (n_vec + block - 1) / block;
    embed_gather_kernel<<<grid, block, 0, stream>>>(
        indices,
        (const float4*)emb,
        (const float4*)oov,
        (float4*)out,
        n_vec, vocab);
}

// Round 2
// 11.868 us; speedup vs baseline: 1.5226x; 1.5226x over previous
//
#include <hip/hip_runtime.h>
#include <hip/hip_bf16.h>

// Embedding gather with OOV handling.
// out[r][d] = (idx[r] >= VOCAB) ? oov[d] : emb[idx[r]][d]
// D = 200 floats = 50 float4 per row; rows are 800B => 16B aligned.
//
// R2: 4 independent float4 per thread (block-contiguous chunks) to get 4x
// memory-level parallelism per thread — R1 was latency-bound on the serial
// idx->emb dependent chain (2.9 TB/s effective vs 6.3 ceiling).
// Nontemporal stores: output is a write-only stream, keep L2 for the gather.

typedef float f32x4 __attribute__((ext_vector_type(4)));

#define ELEMS 4
#define BLOCK 256

__global__ void embed_gather_kernel(const int* __restrict__ indices,
                                    const f32x4* __restrict__ emb,
                                    const f32x4* __restrict__ oov,
                                    f32x4* __restrict__ out,
                                    int n_vec,      // total float4 elements in output
                                    int vocab) {
    int base = blockIdx.x * (BLOCK * ELEMS) + threadIdx.x;

    int   idx[ELEMS];
    int   off[ELEMS];
    f32x4 val[ELEMS];

    // Phase 1: issue all index loads (independent, coalesced-broadcast, L1-hot)
    #pragma unroll
    for (int k = 0; k < ELEMS; ++k) {
        int i = base + k * BLOCK;
        int ii = (i < n_vec) ? i : 0;
        int row = ii / 50;          // magic-mul, cheap
        off[k] = ii - row * 50;
        idx[k] = indices[row];
    }

    // Phase 2: issue all gather loads (independent -> 4 outstanding vmem ops)
    #pragma unroll
    for (int k = 0; k < ELEMS; ++k) {
        const f32x4* src = (idx[k] >= vocab)
                         ? (oov + off[k])
                         : (emb + (long long)idx[k] * 50 + off[k]);
        val[k] = *src;
    }

    // Phase 3: streaming stores
    #pragma unroll
    for (int k = 0; k < ELEMS; ++k) {
        int i = base + k * BLOCK;
        if (i < n_vec) {
            __builtin_nontemporal_store(val[k], out + i);
        }
    }
}

extern "C" void kernel_launch(void* const* d_in, const int* in_sizes, int n_in,
                              void* d_out, int out_size, void* d_ws, size_t ws_size,
                              hipStream_t stream) {
    const int*   indices = (const int*)d_in[0];
    const float* emb     = (const float*)d_in[1];
    const float* oov     = (const float*)d_in[2];
    float*       out     = (float*)d_out;

    const int D      = in_sizes[2];            // 200
    const int vocab  = in_sizes[1] / D;        // 100000
    const int n_vec  = out_size / 4;           // float4 count

    const int grid = (n_vec + BLOCK * ELEMS - 1) / (BLOCK * ELEMS);
    embed_gather_kernel<<<grid, BLOCK, 0, stream>>>(
        indices,
        (const f32x4*)emb,
        (const f32x4*)oov,
        (f32x4*)out,
        n_vec, vocab);
}